// Round 1
// baseline (675.042 us; speedup 1.0000x reference)
//
#include <hip/hip_runtime.h>
#include <stdint.h>

#define NCLS 80
#define CELLS 8400      // 6400 + 1600 + 400
#define PRE 1000
#define KEEP 100
#define CAP 4096
#define NBINS 16384
#define NIMG 32

__device__ __forceinline__ float sigm(float x) { return 1.0f / (1.0f + __expf(-x)); }

__device__ __forceinline__ void lvlinfo(int cell, int& li, int& loc, int& HW) {
  if (cell < 6400)      { li = 0; loc = cell;        HW = 6400; }
  else if (cell < 8000) { li = 1; loc = cell - 6400; HW = 1600; }
  else                  { li = 2; loc = cell - 8000; HW = 400;  }
}

// ---------------- K1: histogram of score bits (scores > 0.25) ----------------
__global__ __launch_bounds__(256) void k_hist(
    const float* __restrict__ cls0, const float* __restrict__ cls1, const float* __restrict__ cls2,
    const float* __restrict__ obj0, const float* __restrict__ obj1, const float* __restrict__ obj2,
    uint32_t* __restrict__ hist) {
  __shared__ uint32_t h[NBINS];
  for (int i = threadIdx.x; i < NBINS; i += 256) h[i] = 0;
  __syncthreads();
  const int b = blockIdx.y;
  const int c0 = (blockIdx.x * 256 + threadIdx.x) * 4;   // 4 cells per thread, level-aligned
  if (c0 < CELLS) {
    int li, loc, HW; lvlinfo(c0, li, loc, HW);
    const float* cls = li == 0 ? cls0 : (li == 1 ? cls1 : cls2);
    const float* obj = li == 0 ? obj0 : (li == 1 ? obj1 : obj2);
    float os[3][4];
#pragma unroll
    for (int p = 0; p < 3; ++p) {
      float4 o = *(const float4*)(obj + ((size_t)b * 3 + p) * HW + loc);
      os[p][0] = sigm(o.x); os[p][1] = sigm(o.y); os[p][2] = sigm(o.z); os[p][3] = sigm(o.w);
    }
    for (int p = 0; p < 3; ++p) {
      const float* cp = cls + ((size_t)b * 240 + p * 80) * HW + loc;
      for (int c = 0; c < 80; ++c) {
        float4 v = *(const float4*)(cp + (size_t)c * HW);
        float sv[4] = { sigm(v.x) * os[p][0], sigm(v.y) * os[p][1],
                        sigm(v.z) * os[p][2], sigm(v.w) * os[p][3] };
#pragma unroll
        for (int k = 0; k < 4; ++k) {
          if (sv[k] > 0.25f) {
            uint32_t key = (__float_as_uint(sv[k]) - 0x3E800000u) >> 10;
            if (key > NBINS - 1) key = NBINS - 1;   // score can round to exactly 1.0f
            atomicAdd(&h[key], 1u);
          }
        }
      }
    }
  }
  __syncthreads();
  for (int i = threadIdx.x; i < NBINS; i += 256) {
    uint32_t v = h[i];
    if (v) atomicAdd(&hist[(size_t)b * NBINS + i], v);
  }
}

// ---------------- K2: find cutoff bin (rank PRE from the top) ----------------
__global__ __launch_bounds__(256) void k_cutoff(const uint32_t* __restrict__ hist,
                                                uint32_t* __restrict__ cutoff) {
  __shared__ uint32_t seg[256];
  const int b = blockIdx.x;
  const uint32_t* hb = hist + (size_t)b * NBINS;
  uint32_t s = 0;
  for (int k = 0; k < 64; ++k) s += hb[threadIdx.x * 64 + k];
  seg[threadIdx.x] = s;
  __syncthreads();
  if (threadIdx.x == 0) {
    uint32_t acc = 0; int segi = -1;
    for (int i = 255; i >= 0; --i) {
      if (acc + seg[i] >= (uint32_t)PRE) { segi = i; break; }
      acc += seg[i];
    }
    uint32_t cut = 0;
    if (segi >= 0) {
      for (int k = 63; k >= 0; --k) {
        acc += hb[segi * 64 + k];
        if (acc >= (uint32_t)PRE) { cut = (uint32_t)(segi * 64 + k); break; }
      }
    }
    cutoff[b] = cut;
  }
}

// ---------------- K3: collect candidates with key >= cutoff ----------------
__global__ __launch_bounds__(256) void k_collect(
    const float* __restrict__ cls0, const float* __restrict__ cls1, const float* __restrict__ cls2,
    const float* __restrict__ obj0, const float* __restrict__ obj1, const float* __restrict__ obj2,
    const uint32_t* __restrict__ cutoff, uint32_t* __restrict__ candCount,
    uint64_t* __restrict__ cand) {
  const int b = blockIdx.y;
  const int c0 = (blockIdx.x * 256 + threadIdx.x) * 4;
  if (c0 >= CELLS) return;
  const uint32_t cut = cutoff[b];
  int li, loc, HW; lvlinfo(c0, li, loc, HW);
  const float* cls = li == 0 ? cls0 : (li == 1 ? cls1 : cls2);
  const float* obj = li == 0 ? obj0 : (li == 1 ? obj1 : obj2);
  float os[3][4];
#pragma unroll
  for (int p = 0; p < 3; ++p) {
    float4 o = *(const float4*)(obj + ((size_t)b * 3 + p) * HW + loc);
    os[p][0] = sigm(o.x); os[p][1] = sigm(o.y); os[p][2] = sigm(o.z); os[p][3] = sigm(o.w);
  }
  for (int p = 0; p < 3; ++p) {
    const float* cp = cls + ((size_t)b * 240 + p * 80) * HW + loc;
    for (int c = 0; c < 80; ++c) {
      float4 v = *(const float4*)(cp + (size_t)c * HW);
      float sv[4] = { sigm(v.x) * os[p][0], sigm(v.y) * os[p][1],
                      sigm(v.z) * os[p][2], sigm(v.w) * os[p][3] };
#pragma unroll
      for (int k = 0; k < 4; ++k) {
        float sk = sv[k];
        if (sk > 0.25f) {
          uint32_t key = (__float_as_uint(sk) - 0x3E800000u) >> 10;   // >=16384 only for s==1.0
          if (key >= cut) {
            uint32_t pos = atomicAdd(&candCount[b], 1u);
            if (pos < CAP) {
              uint32_t flat = (uint32_t)((((c0 + k) * 3 + p) * 80) + c);
              cand[(size_t)b * CAP + pos] =
                  ((uint64_t)__float_as_uint(sk) << 32) | (uint64_t)(0xFFFFFFFFu - flat);
            }
          }
        }
      }
    }
  }
}

// ---------------- K4: per-image bitonic sort + take top-1000 + decode boxes ----------------
__global__ __launch_bounds__(1024) void k_sort_decode(
    const uint64_t* __restrict__ cand, const uint32_t* __restrict__ candCount,
    const float* __restrict__ bbox0, const float* __restrict__ bbox1, const float* __restrict__ bbox2,
    const float* __restrict__ priors, const float* __restrict__ strides,
    float* __restrict__ topS, int* __restrict__ topLab, float* __restrict__ topBox,
    uint32_t* __restrict__ nvArr) {
  __shared__ uint64_t s[CAP];
  const int b = blockIdx.x;
  uint32_t cnt = candCount[b]; if (cnt > (uint32_t)CAP) cnt = CAP;
  for (int i = threadIdx.x; i < CAP; i += 1024)
    s[i] = (i < (int)cnt) ? cand[(size_t)b * CAP + i] : 0ull;
  __syncthreads();
  for (int k = 2; k <= CAP; k <<= 1) {
    for (int j = k >> 1; j > 0; j >>= 1) {
      for (int i = threadIdx.x; i < CAP; i += 1024) {
        int p = i ^ j;
        if (p > i) {
          uint64_t a = s[i], c = s[p];
          bool asc = (i & k) != 0;
          if (asc ? (a > c) : (a < c)) { s[i] = c; s[p] = a; }
        }
      }
      __syncthreads();
    }
  }
  const int NV = (int)(cnt < (uint32_t)PRE ? cnt : (uint32_t)PRE);
  if (threadIdx.x == 0) nvArr[b] = (uint32_t)NV;
  for (int t = threadIdx.x; t < PRE; t += 1024) {
    float sc = 0.0f; int lab = 0; float b0 = 0, b1 = 0, b2v = 0, b3 = 0;
    if (t < NV) {
      uint64_t key = s[t];
      sc = __uint_as_float((uint32_t)(key >> 32));
      uint32_t flat = 0xFFFFFFFFu - (uint32_t)(key & 0xFFFFFFFFull);
      uint32_t n = flat / 80u; lab = (int)(flat - n * 80u);
      uint32_t g = n / 3u; uint32_t p = n - g * 3u;
      int li, loc, HW; lvlinfo((int)g, li, loc, HW);
      const float* bb = li == 0 ? bbox0 : (li == 1 ? bbox1 : bbox2);
      size_t o = ((size_t)b * 12 + p * 4) * HW + loc;
      float p0 = sigm(bb[o]);
      float p1 = sigm(bb[o + (size_t)HW]);
      float p2 = sigm(bb[o + 2 * (size_t)HW]);
      float p3 = sigm(bb[o + 3 * (size_t)HW]);
      float4 pr = *(const float4*)(priors + (size_t)n * 4);
      float st = strides[n];
      float cx = (pr.x + pr.z) * 0.5f, cy = (pr.y + pr.w) * 0.5f;
      float w = pr.z - pr.x, hh = pr.w - pr.y;
      float xc = (p0 - 0.5f) * 2.0f * st + cx;
      float yc = (p1 - 0.5f) * 2.0f * st + cy;
      float wp = p2 * 2.0f; wp = wp * wp * w;
      float hp = p3 * 2.0f; hp = hp * hp * hh;
      b0 = xc - wp * 0.5f; b1 = yc - hp * 0.5f; b2v = xc + wp * 0.5f; b3 = yc + hp * 0.5f;
    }
    topS[(size_t)b * PRE + t] = sc;
    topLab[(size_t)b * PRE + t] = lab;
    *(float4*)(topBox + ((size_t)b * PRE + t) * 4) = make_float4(b0, b1, b2v, b3);
  }
}

// ---------------- K5: IoU suppression bitmask (j > i, same label, iou > thr) ----------------
__global__ __launch_bounds__(256) void k_iou(
    const float* __restrict__ topBox, const int* __restrict__ topLab,
    const uint32_t* __restrict__ nvArr, uint64_t* __restrict__ mask) {
  __shared__ float4 bx[PRE];
  __shared__ int lb[PRE];
  const int b = blockIdx.y;
  const int NV = (int)nvArr[b];
  for (int i = threadIdx.x; i < PRE; i += 256) {
    bx[i] = *(const float4*)(topBox + ((size_t)b * PRE + i) * 4);
    lb[i] = topLab[(size_t)b * PRE + i];
  }
  __syncthreads();
  for (int task = blockIdx.x * 256 + threadIdx.x; task < PRE * 16; task += gridDim.x * 256) {
    const int i = task >> 4, w = task & 15;
    uint64_t m = 0;
    if (i < NV) {
      const float4 a = bx[i]; const int la = lb[i];
      const float areaA = (a.z - a.x) * (a.w - a.y);
      const int j0 = w << 6;
      const int jend = (j0 + 64 < NV) ? j0 + 64 : NV;
      for (int j = (j0 > i + 1 ? j0 : i + 1); j < jend; ++j) {
        if (lb[j] != la) continue;
        const float4 c = bx[j];
        float xx1 = fmaxf(a.x, c.x), yy1 = fmaxf(a.y, c.y);
        float xx2 = fminf(a.z, c.z), yy2 = fminf(a.w, c.w);
        float iw = fmaxf(xx2 - xx1, 0.0f), ih = fmaxf(yy2 - yy1, 0.0f);
        float inter = iw * ih;
        float areaB = (c.z - c.x) * (c.w - c.y);
        float iou = inter / (areaA + areaB - inter + 1e-7f);
        if (iou > 0.65f) m |= (1ull << (j - j0));
      }
    }
    mask[((size_t)b * PRE + i) * 16 + w] = m;
  }
}

// ---------------- K6: serial greedy scan + output assembly ----------------
__global__ __launch_bounds__(256) void k_scan_out(
    const uint64_t* __restrict__ mask, const float* __restrict__ topS,
    const int* __restrict__ topLab, const float* __restrict__ topBox,
    const uint32_t* __restrict__ nvArr, float* __restrict__ out) {
  __shared__ uint64_t rows[PRE * 16];   // 125 KB
  __shared__ uint64_t keepw[16];
  __shared__ uint32_t pref[17];
  const int b = blockIdx.x;
  const int NV = (int)nvArr[b];
  for (int i = threadIdx.x; i < NV * 16; i += 256) rows[i] = mask[(size_t)b * PRE * 16 + i];
  __syncthreads();
  if (threadIdx.x < 64) {
    const int lane = threadIdx.x;
    uint64_t remv = 0, kw = 0;
    for (int w0 = 0; w0 * 64 < NV; ++w0) {
      uint64_t cur = (uint64_t)__shfl((unsigned long long)remv, w0);  // wave-uniform test word
      const int ie = (w0 * 64 + 64 < NV) ? w0 * 64 + 64 : NV;
      for (int i = w0 * 64; i < ie; ++i) {
        const int bi = i & 63;
        if (!((cur >> bi) & 1ull)) {
          uint64_t rl = rows[i * 16 + (lane & 15)];
          cur |= rows[i * 16 + w0];
          if (lane < 16) remv |= rl;
          if (lane == w0) kw |= (1ull << bi);
        }
      }
    }
    if (lane < 16) keepw[lane] = kw;
  }
  __syncthreads();
  if (threadIdx.x == 0) {
    uint32_t a = 0;
    for (int w = 0; w < 16; ++w) { pref[w] = a; a += (uint32_t)__popcll((unsigned long long)keepw[w]); }
    pref[16] = a;
  }
  __syncthreads();
  const uint32_t total = pref[16];
  const uint32_t num = total < (uint32_t)KEEP ? total : (uint32_t)KEEP;
  float* o_num = out;                       // [32] (int ref written as float)
  float* o_box = out + NIMG;                // [32][100][4]
  float* o_s   = out + NIMG + NIMG * KEEP * 4;
  float* o_l   = o_s + NIMG * KEEP;
  if (threadIdx.x == 0) o_num[b] = (float)num;
  const int zstart = NV < KEEP ? NV : KEEP; // slots < min(NV,100) are written exactly once below
  for (int sidx = zstart + threadIdx.x; sidx < KEEP; sidx += 256) {
    ((float4*)o_box)[b * KEEP + sidx] = make_float4(0, 0, 0, 0);
    o_s[b * KEEP + sidx] = 0.0f;
    o_l[b * KEEP + sidx] = 0.0f;
  }
  for (int j = threadIdx.x; j < NV; j += 256) {
    const int wi = j >> 6, bi = j & 63;
    const uint64_t kword = keepw[wi];
    const int isk = (int)((kword >> bi) & 1ull);
    const uint32_t below = pref[wi] + (uint32_t)__popcll((unsigned long long)(kword & ((1ull << bi) - 1ull)));
    const uint32_t slot = isk ? below : (total + (uint32_t)j - below);
    if (slot < (uint32_t)KEEP) {
      ((float4*)o_box)[b * KEEP + slot] = *(const float4*)(topBox + ((size_t)b * PRE + j) * 4);
      o_s[b * KEEP + slot] = isk ? topS[(size_t)b * PRE + j] : 0.0f;
      o_l[b * KEEP + slot] = (float)topLab[(size_t)b * PRE + j];
    }
  }
}

extern "C" void kernel_launch(void* const* d_in, const int* in_sizes, int n_in,
                              void* d_out, int out_size, void* d_ws, size_t ws_size,
                              hipStream_t stream) {
  (void)in_sizes; (void)n_in; (void)out_size; (void)ws_size;
  const float* cls0 = (const float*)d_in[0];
  const float* cls1 = (const float*)d_in[1];
  const float* cls2 = (const float*)d_in[2];
  const float* bbox0 = (const float*)d_in[3];
  const float* bbox1 = (const float*)d_in[4];
  const float* bbox2 = (const float*)d_in[5];
  const float* obj0 = (const float*)d_in[6];
  const float* obj1 = (const float*)d_in[7];
  const float* obj2 = (const float*)d_in[8];
  const float* priors = (const float*)d_in[9];
  const float* strides = (const float*)d_in[10];
  float* out = (float*)d_out;

  char* ws = (char*)d_ws;
  size_t off = 0;
  auto alloc = [&](size_t bytes) -> void* {
    void* p = ws + off;
    off = (off + bytes + 255) & ~(size_t)255;
    return p;
  };
  uint32_t* hist      = (uint32_t*)alloc((size_t)NIMG * NBINS * 4);   // 2 MB
  uint32_t* candCount = (uint32_t*)alloc(NIMG * 4);
  uint32_t* cutoff    = (uint32_t*)alloc(NIMG * 4);
  uint64_t* cand      = (uint64_t*)alloc((size_t)NIMG * CAP * 8);     // 1 MB
  uint32_t* nvArr     = (uint32_t*)alloc(NIMG * 4);
  float*    topS      = (float*)alloc((size_t)NIMG * PRE * 4);
  int*      topLab    = (int*)alloc((size_t)NIMG * PRE * 4);
  float*    topBox    = (float*)alloc((size_t)NIMG * PRE * 16);
  uint64_t* maskbuf   = (uint64_t*)alloc((size_t)NIMG * PRE * 16 * 8); // 4 MB

  hipMemsetAsync(hist, 0, (size_t)NIMG * NBINS * 4, stream);
  hipMemsetAsync(candCount, 0, NIMG * 4, stream);

  dim3 gScan(9, NIMG);   // 9 blocks * 256 threads * 4 cells = 9216 >= 8400 cells
  k_hist<<<gScan, 256, 0, stream>>>(cls0, cls1, cls2, obj0, obj1, obj2, hist);
  k_cutoff<<<NIMG, 256, 0, stream>>>(hist, cutoff);
  k_collect<<<gScan, 256, 0, stream>>>(cls0, cls1, cls2, obj0, obj1, obj2,
                                       cutoff, candCount, cand);
  k_sort_decode<<<NIMG, 1024, 0, stream>>>(cand, candCount, bbox0, bbox1, bbox2,
                                           priors, strides, topS, topLab, topBox, nvArr);
  k_iou<<<dim3(8, NIMG), 256, 0, stream>>>(topBox, topLab, nvArr, maskbuf);
  k_scan_out<<<NIMG, 256, 0, stream>>>(maskbuf, topS, topLab, topBox, nvArr, out);
}